// Round 1
// 6574.197 us; speedup vs baseline: 1.6052x; 1.6052x over previous
//
#include <hip/hip_runtime.h>

// ---------------------------------------------------------------------------
// LanguageModel: embed -> LSTM(1024) x2 -> last-step logits(32000) -> softmax
// B=64, S=512, E=512, H=1024, G=4H=4096, V=32000
//
// Round 5:
//  - lstm_layer waves repartitioned (row-tile x K-half) instead of
//    (row-tile x col-tile): h-broadcast sc1 traffic halved, 32->16 MB/step
//    (the fabric-BW bottleneck: 32MB / 5.57us = 5.9 TB/s, at the ceiling).
//    K-half partial sums reduce through the existing gx LDS buffer.
//  - x4s prefetch hoisted above the MFMA loop (hide ~900cy HBM latency).
//  - GEMM virtual row order changed to r = s*64 + batch: each gemm_bias<1>
//    block now owns a contiguous 8KB x4s region -> LDS-transpose epilogue
//    with 2x16B stores/thread (was 16 false-shared 2B stores/thread).
//    embed_pack gather index and lstm h1A write updated to match.
//  - Coherence/sync structure unchanged (fence-free, relaxed sc1 + flags).
// ---------------------------------------------------------------------------

#define BB 64
#define SS 512
#define EE 512
#define HH 1024
#define GG 4096
#define VV 32000

using bf16x8 = __attribute__((ext_vector_type(8))) __bf16;
using f32x4  = __attribute__((ext_vector_type(4))) float;

__device__ __forceinline__ unsigned short f2bf(float f) {
    unsigned u = __float_as_uint(f);
    unsigned r = u + 0x7FFFu + ((u >> 16) & 1u);   // RNE
    return (unsigned short)(r >> 16);
}
__device__ __forceinline__ float bf2f(unsigned short u) {
    return __uint_as_float(((unsigned)u) << 16);
}
__device__ __forceinline__ float sigm(float x) {
    return 1.0f / (1.0f + expf(-x));
}
// 16B fragment load via two agent-scope relaxed atomics (sc1 -> coherent at IF).
__device__ __forceinline__ bf16x8 ld_frag_coh(const unsigned long long* p) {
    union { unsigned long long u[2]; bf16x8 v; } x;
    x.u[0] = __hip_atomic_load(p,     __ATOMIC_RELAXED, __HIP_MEMORY_SCOPE_AGENT);
    x.u[1] = __hip_atomic_load(p + 1, __ATOMIC_RELAXED, __HIP_MEMORY_SCOPE_AGENT);
    return x.v;
}

// Packed-B layout: elem(nt, kt, lane, j) = B[kt*32 + (lane>>4)*8 + j][nt*16 + (lane&15)]
__global__ void pack_b(const float* __restrict__ B, unsigned short* __restrict__ out,
                       int KT, int N) {
    int bid = blockIdx.x;          // = nt*KT + kt
    int lane = threadIdx.x;
    int nt = bid / KT, kt = bid % KT;
    int k = kt * 32 + ((lane >> 4) << 3);
    int n = nt * 16 + (lane & 15);
    size_t base = ((size_t)bid * 64 + lane) * 8;
    #pragma unroll
    for (int j = 0; j < 8; ++j)
        out[base + j] = f2bf(B[(size_t)(k + j) * N + n]);
}

// Wh pack: colgroup g in [0,128) owns h-cols 8g..8g+7
// -> 32 gate-cols ordered n = q*8+cj (q=gate, cj=col offset), as 2 n-tiles.
// Frag id f = (g*2 + nt)*32 + kt.
__global__ void pack_wh(const float* __restrict__ Wh, unsigned short* __restrict__ out) {
    int f = blockIdx.x;            // (g*2 + nt)*32 + kt ; grid 8192
    int lane = threadIdx.x;
    int kt = f & 31, nt = (f >> 5) & 1, g = f >> 6;
    int nloc = lane & 15;
    int q = nt * 2 + (nloc >> 3), cj = nloc & 7;
    int gcol = q * HH + 8 * g + cj;
    int k = kt * 32 + ((lane >> 4) << 3);
    size_t base = ((size_t)f * 64 + lane) * 8;
    #pragma unroll
    for (int j = 0; j < 8; ++j)
        out[base + j] = f2bf(Wh[(size_t)(k + j) * GG + gcol]);
}

// Embedding gather written directly in packed-A form (M=32768 rows, K=512).
// Row order r = s*64 + b  (s-major, batch innermost).
__global__ void embed_pack(const int* __restrict__ x, const float* __restrict__ tab,
                           unsigned short* __restrict__ out) {
    int bid = blockIdx.x;          // = mt*16 + kt  (KT=16)
    int lane = threadIdx.x;
    int mt = bid >> 4, kt = bid & 15;
    int m = mt * 16 + (lane & 15);            // r = s*64 + b
    int idx = x[(m & 63) * SS + (m >> 6)];    // x is [B][S]
    int kb = kt * 32 + ((lane >> 4) << 3);
    size_t base = ((size_t)bid * 64 + lane) * 8;
    const float* src = tab + (size_t)idx * EE + kb;
    #pragma unroll
    for (int j = 0; j < 8; ++j)
        out[base + j] = f2bf(src[j]);
}

// C = A@B + bias.  MODE 0: float row-major (logits).
//                  MODE 1: bf16 x4s layout out[((s*GG + col)*64 + batch)],
//                          virtual row r = s*64 + batch; block owns one s x
//                          64 cols x 64 batches = contiguous 8KB region.
template<int MODE>
__global__ __launch_bounds__(256) void gemm_bias(
    const unsigned short* __restrict__ Ap, const unsigned short* __restrict__ Bp,
    const float* __restrict__ bias, void* __restrict__ Cout, int N, int KT) {
    __shared__ unsigned short tile[64][72];   // MODE1 transpose staging (padded)
    const int tid = threadIdx.x, lane = tid & 63, w = tid >> 6;
    const int ntg = blockIdx.x * 4 + w;
    const int m0t = blockIdx.y * 4;
    const bf16x8* Av = reinterpret_cast<const bf16x8*>(Ap);
    const bf16x8* Bv = reinterpret_cast<const bf16x8*>(Bp);
    f32x4 acc[4] = {{0.f,0.f,0.f,0.f},{0.f,0.f,0.f,0.f},{0.f,0.f,0.f,0.f},{0.f,0.f,0.f,0.f}};
    for (int kt = 0; kt < KT; ++kt) {
        bf16x8 b = Bv[((size_t)ntg * KT + kt) * 64 + lane];
        #pragma unroll
        for (int mt = 0; mt < 4; ++mt) {
            bf16x8 a = Av[((size_t)(m0t + mt) * KT + kt) * 64 + lane];
            acc[mt] = __builtin_amdgcn_mfma_f32_16x16x32_bf16(a, b, acc[mt], 0, 0, 0);
        }
    }
    const int col = ntg * 16 + (lane & 15);
    const int rq = (lane >> 4) << 2;
    const float bb = bias[col];
    if (MODE == 0) {
        #pragma unroll
        for (int mt = 0; mt < 4; ++mt)
            #pragma unroll
            for (int i = 0; i < 4; ++i) {
                int row = (m0t + mt) * 16 + rq + i;
                ((float*)Cout)[(size_t)row * N + col] = acc[mt][i] + bb;
            }
    } else {
        const int cl = w * 16 + (lane & 15);            // block-local col
        #pragma unroll
        for (int mt = 0; mt < 4; ++mt)
            #pragma unroll
            for (int i = 0; i < 4; ++i)
                tile[cl][mt * 16 + rq + i] = f2bf(acc[mt][i] + bb);
        __syncthreads();
        // linear 8KB store: out element (s*GG + col0)*64 + c*64 + b
        const int c = tid >> 2, b0 = (tid & 3) << 4;
        unsigned short* dst = (unsigned short*)Cout +
            ((size_t)blockIdx.y * GG + (size_t)blockIdx.x * 64) * 64 + (size_t)tid * 16;
        const uint4* s4 = reinterpret_cast<const uint4*>(&tile[c][b0]);
        reinterpret_cast<uint4*>(dst)[0] = s4[0];
        reinterpret_cast<uint4*>(dst)[1] = s4[1];
    }
}

// Zero h0 for both layers + all barrier flags.
__global__ void zero_init(unsigned short* __restrict__ h0a,
                          unsigned short* __restrict__ h0b,
                          unsigned int* __restrict__ flags) {
    int i = blockIdx.x * 256 + threadIdx.x;      // grid 64 x 256
    for (int k = i; k < BB * HH; k += 64 * 256) { h0a[k] = 0; h0b[k] = 0; }
    for (int k = i; k < 8192; k += 64 * 256) flags[k] = 0;
}

// Persistent LSTM layer. Grid 256 x 256 (cooperative).
// Block b: g = b>>1 (h-cols 8g..8g+7 -> 32 gate-cols), hf = b&1 (batch rows 32hf..+31).
// Waves: msub = w&1 (row-tile), kh = w>>1 (K-half) -> disjoint A fragments
// (64KB/block/step sc1 traffic, the minimum), both n-tiles per wave,
// K-half partial sums reduced through gx[2] in the elementwise phase.
__global__ __launch_bounds__(256, 1) void lstm_layer(
    const unsigned short* __restrict__ x4s, const unsigned short* __restrict__ whp,
    unsigned short* __restrict__ hbA, unsigned short* __restrict__ hbB,
    unsigned short* __restrict__ h1A, unsigned int* __restrict__ flagsL) {
    __shared__ float gx[2][32][36];                         // [khalf][n][block-row]
    __shared__ __align__(16) unsigned short hlds[32][8];    // gathered h chunks
    __shared__ __align__(16) unsigned short Blds[128 * 64 * 8];  // 64 KB Wh slice
    const int tid = threadIdx.x, lane = tid & 63, w = tid >> 6;
    const int g = blockIdx.x >> 1, hf = blockIdx.x & 1;
    unsigned int* flags = flagsL + hf * 2048;               // 128 flags x 16 u32 pad

    // ---- stage this colgroup's Wh slice (64 KB) into LDS, once ----
    {
        const uint4* src = reinterpret_cast<const uint4*>(whp) + (size_t)g * 4096;
        uint4* dst = reinterpret_cast<uint4*>(Blds);
        #pragma unroll
        for (int i = 0; i < 16; ++i)
            dst[i * 256 + tid] = src[i * 256 + tid];
    }
    __syncthreads();
    const bf16x8* Bl = reinterpret_cast<const bf16x8*>(Blds);

    const int msub = w & 1, kh = w >> 1;
    const int nloc = lane & 15;
    const int cj = nloc & 7;
    const int q0 = nloc >> 3;                               // gate idx for nt=0
    const int gq0 = q0 * HH + 8 * g + cj;                   // nt=0 gate col
    const int gq1 = (2 + q0) * HH + 8 * g + cj;             // nt=1 gate col
    const int rbase = msub * 16 + ((lane >> 4) << 2);       // block-local row base
    const size_t afrag_base = ((size_t)(2 * hf + msub) * 32 + (size_t)kh * 16) * 64 + lane;

    // elementwise thread mapping
    const int row_l = tid >> 3, cj2 = tid & 7;
    float c = 0.f;

    #pragma unroll 1
    for (int t = 0; t < SS; ++t) {
        const unsigned long long* hv =
            reinterpret_cast<const unsigned long long*>((t & 1) ? hbB : hbA);
        unsigned short* hout = (t & 1) ? hbA : hbB;

        // prefetch x4 for this step (kh==0 waves only; independent of h)
        ushort4 xv0, xv1;
        if (kh == 0) {
            xv0 = *reinterpret_cast<const ushort4*>(
                x4s + ((size_t)t * GG + gq0) * 64 + 32 * hf + rbase);
            xv1 = *reinterpret_cast<const ushort4*>(
                x4s + ((size_t)t * GG + gq1) * 64 + 32 * hf + rbase);
        }

        f32x4 acc0 = {0.f, 0.f, 0.f, 0.f}, acc1 = {0.f, 0.f, 0.f, 0.f};
        #pragma unroll
        for (int k = 0; k < 16; ++k) {
            const int kt = kh * 16 + k;
            bf16x8 a = ld_frag_coh(hv + (afrag_base + (size_t)k * 64) * 2);
            acc0 = __builtin_amdgcn_mfma_f32_16x16x32_bf16(
                a, Bl[(0 * 32 + kt) * 64 + lane], acc0, 0, 0, 0);
            acc1 = __builtin_amdgcn_mfma_f32_16x16x32_bf16(
                a, Bl[(1 * 32 + kt) * 64 + lane], acc1, 0, 0, 0);
        }

        // write K-half partial sums (kh0 adds the x-projection)
        if (kh == 0) {
            gx[0][nloc][rbase + 0] = acc0[0] + bf2f(xv0.x);
            gx[0][nloc][rbase + 1] = acc0[1] + bf2f(xv0.y);
            gx[0][nloc][rbase + 2] = acc0[2] + bf2f(xv0.z);
            gx[0][nloc][rbase + 3] = acc0[3] + bf2f(xv0.w);
            gx[0][16 + nloc][rbase + 0] = acc1[0] + bf2f(xv1.x);
            gx[0][16 + nloc][rbase + 1] = acc1[1] + bf2f(xv1.y);
            gx[0][16 + nloc][rbase + 2] = acc1[2] + bf2f(xv1.z);
            gx[0][16 + nloc][rbase + 3] = acc1[3] + bf2f(xv1.w);
        } else {
            gx[1][nloc][rbase + 0] = acc0[0];
            gx[1][nloc][rbase + 1] = acc0[1];
            gx[1][nloc][rbase + 2] = acc0[2];
            gx[1][nloc][rbase + 3] = acc0[3];
            gx[1][16 + nloc][rbase + 0] = acc1[0];
            gx[1][16 + nloc][rbase + 1] = acc1[1];
            gx[1][16 + nloc][rbase + 2] = acc1[2];
            gx[1][16 + nloc][rbase + 3] = acc1[3];
        }
        __syncthreads();

        // elementwise: thread -> (row_l, cj2); n = q*8 + cj
        float gi = gx[0][0 * 8 + cj2][row_l] + gx[1][0 * 8 + cj2][row_l];
        float gf = gx[0][1 * 8 + cj2][row_l] + gx[1][1 * 8 + cj2][row_l];
        float gg = gx[0][2 * 8 + cj2][row_l] + gx[1][2 * 8 + cj2][row_l];
        float go = gx[0][3 * 8 + cj2][row_l] + gx[1][3 * 8 + cj2][row_l];
        float cn = sigm(gf) * c + sigm(gi) * tanhf(gg);
        c = cn;
        hlds[row_l][cj2] = f2bf(sigm(go) * tanhf(cn));
        __syncthreads();

        // gather 16B chunks; one full line per 4 rows, all owned by this block
        if (tid < 32) {
            union { uint4 v; unsigned long long u[2]; } cv;
            cv.v = *reinterpret_cast<const uint4*>(&hlds[tid][0]);
            const int m = 32 * hf + tid;
            unsigned long long* dst = reinterpret_cast<unsigned long long*>(
                hout + (((size_t)(m >> 4) * 32 + (g >> 2)) * 64 + (g & 3) * 16 + (m & 15)) * 8);
            __hip_atomic_store(dst,     cv.u[0], __ATOMIC_RELAXED, __HIP_MEMORY_SCOPE_AGENT);
            __hip_atomic_store(dst + 1, cv.u[1], __ATOMIC_RELAXED, __HIP_MEMORY_SCOPE_AGENT);
            if (h1A) {   // packed-A row r = t*64 + m (s-major order)
                const size_t mg = (size_t)t * 64 + m;
                *reinterpret_cast<uint4*>(
                    h1A + (((mg >> 4) * 32 + (size_t)(g >> 2)) * 64 + (g & 3) * 16 + (mg & 15)) * 8) = cv.v;
            }
        }

        // ---- release: drain own stores; no cache ops ----
        asm volatile("s_waitcnt vmcnt(0)" ::: "memory");
        __syncthreads();
        if (tid == 0)
            __hip_atomic_store(&flags[g * 16], (unsigned)(t + 1),
                               __ATOMIC_RELAXED, __HIP_MEMORY_SCOPE_AGENT);
        if (tid < 128) {
            while (__hip_atomic_load(&flags[tid * 16], __ATOMIC_RELAXED,
                                     __HIP_MEMORY_SCOPE_AGENT) < (unsigned)(t + 1))
                __builtin_amdgcn_s_sleep(1);
        }
        __syncthreads();
    }
}

__global__ __launch_bounds__(256) void softmax_rows(const float* __restrict__ logits,
                                                    float* __restrict__ out) {
    __shared__ float red[256];
    int rr = blockIdx.x, tid = threadIdx.x;
    const float* L = logits + (size_t)rr * VV;
    float m = -1e30f;
    for (int i = tid; i < VV; i += 256) m = fmaxf(m, L[i]);
    red[tid] = m; __syncthreads();
    for (int s = 128; s > 0; s >>= 1) { if (tid < s) red[tid] = fmaxf(red[tid], red[tid + s]); __syncthreads(); }
    m = red[0]; __syncthreads();
    float sum = 0.f;
    for (int i = tid; i < VV; i += 256) sum += expf(L[i] - m);
    red[tid] = sum; __syncthreads();
    for (int s = 128; s > 0; s >>= 1) { if (tid < s) red[tid] += red[tid + s]; __syncthreads(); }
    float inv = 1.f / red[0];
    for (int i = tid; i < VV; i += 256) out[(size_t)rr * VV + i] = expf(L[i] - m) * inv;
}

extern "C" void kernel_launch(void* const* d_in, const int* in_sizes, int n_in,
                              void* d_out, int out_size, void* d_ws, size_t ws_size,
                              hipStream_t stream) {
    const int*   x    = (const int*)  d_in[0];
    const float* tab  = (const float*)d_in[1];
    const float* Wx0  = (const float*)d_in[2];
    const float* Wh0  = (const float*)d_in[3];
    const float* b0   = (const float*)d_in[4];
    const float* Wx1  = (const float*)d_in[5];
    const float* Wh1  = (const float*)d_in[6];
    const float* b1   = (const float*)d_in[7];
    const float* Wout = (const float*)d_in[8];
    const float* bout = (const float*)d_in[9];
    float* out = (float*)d_out;

    // ---- workspace layout (ushort units); all segments 16B-aligned ----
    unsigned short* ws    = (unsigned short*)d_ws;
    unsigned short* embA  = ws;                    // 16,777,216
    unsigned short* wx0p  = embA  + 16777216;      //  2,097,152
    unsigned short* wh0p  = wx0p  + 2097152;       //  4,194,304
    unsigned short* wx1p  = wh0p  + 4194304;       //  4,194,304
    unsigned short* wh1p  = wx1p  + 4194304;       //  4,194,304
    unsigned short* woutp = wh1p  + 4194304;       // 32,768,000
    unsigned short* x4s   = woutp + 32768000;      // 134,217,728 (reused by both layers)
    unsigned short* h1A   = x4s   + 134217728;     // 33,554,432
    unsigned short* hb0   = h1A   + 33554432;      // 65,536  (layer 0)
    unsigned short* hb1   = hb0   + 65536;         // 65,536
    unsigned short* hb2   = hb1   + 65536;         // 65,536  (layer 1)
    unsigned short* hb3   = hb2   + 65536;         // 65,536
    float* logits = (float*)(hb3 + 65536);         // 2,048,000 f32
    unsigned int* flags = (unsigned int*)(logits + 2048000);  // 8192 u32 (2 layers x 2 halves x 128 x 16)
    // total ~472 MB

    // ---- weight packing ----
    pack_b <<<256 * 16, 64, 0, stream>>>(Wx0, wx0p, 16, GG);
    pack_wh<<<8192, 64, 0, stream>>>(Wh0, wh0p);
    pack_b <<<256 * 32, 64, 0, stream>>>(Wx1, wx1p, 32, GG);
    pack_wh<<<8192, 64, 0, stream>>>(Wh1, wh1p);
    pack_b <<<2000 * 32, 64, 0, stream>>>(Wout, woutp, 32, VV);

    // ---- h0 + flag init ----
    zero_init<<<64, 256, 0, stream>>>(hb0, hb2, flags);

    // ---- embedding + layer-0 input projection ----
    embed_pack<<<32768, 64, 0, stream>>>(x, tab, embA);
    gemm_bias<1><<<dim3(GG / 64, 32768 / 64), 256, 0, stream>>>(embA, wx0p, b0, x4s, GG, EE / 32);

    // ---- layer 0 recurrence (persistent cooperative) ----
    {
        const unsigned short* a0 = x4s; const unsigned short* a1 = wh0p;
        unsigned short *a2 = hb0, *a3 = hb1, *a4 = h1A;
        unsigned int* a5 = flags;
        void* args[] = {&a0, &a1, &a2, &a3, &a4, &a5};
        hipLaunchCooperativeKernel((const void*)lstm_layer, dim3(256), dim3(256),
                                   args, 0, stream);
    }

    // ---- layer-1 input projection + recurrence ----
    gemm_bias<1><<<dim3(GG / 64, 32768 / 64), 256, 0, stream>>>(h1A, wx1p, b1, x4s, GG, HH / 32);
    {
        const unsigned short* a0 = x4s; const unsigned short* a1 = wh1p;
        unsigned short *a2 = hb2, *a3 = hb3, *a4 = nullptr;
        unsigned int* a5 = flags + 4096;
        void* args[] = {&a0, &a1, &a2, &a3, &a4, &a5};
        hipLaunchCooperativeKernel((const void*)lstm_layer, dim3(256), dim3(256),
                                   args, 0, stream);
    }
    // t=511 (odd) writes hb2

    // ---- logits (last timestep) + softmax ----
    gemm_bias<0><<<dim3(VV / 64, 1), 256, 0, stream>>>(hb2, woutp, bout, logits, VV, HH / 32);
    softmax_rows<<<64, 256, 0, stream>>>(logits, out);
}

// Round 3
// 5933.343 us; speedup vs baseline: 1.7785x; 1.1080x over previous
//
#include <hip/hip_runtime.h>

// ---------------------------------------------------------------------------
// LanguageModel: embed -> LSTM(1024) x2 -> last-step logits(32000) -> softmax
// B=64, S=512, E=512, H=1024, G=4H=4096, V=32000
//
// Round 7 (fix round-6 NaN, keep the latency attack):
//  - Round-6 NaN root cause: inline-asm global_load + hand-counted vmcnt --
//    MFMA could consume load-dest registers via regalloc copies before data
//    landed. Reverted to the PROVEN __hip_atomic_load pair loads.
//  - Latency fix kept, safely: all 16 h-fragments are loaded into a register
//    array BEFORE any MFMA (source-level hoist). Atomic loads issue in order
//    back-to-back; the compiler inserts its own counted waits before first
//    use -> ONE ~700cy IF-latency window per step instead of 16 serialized
//    ones (round-5 step time 4.93us ~= 16 x 700cy, the smoking gun).
//  - 2-hop leader barrier kept (audited: IF is a single serialization point;
//    done-flags stored after vmcnt(0) drain; go stored after observing all
//    done-flags). Kills the ~6.7 TB/s poll storm of the 256x128-lane spin.
//  - x4s prefetch: plain HIP loads placed after the h-load issue.
// ---------------------------------------------------------------------------

#define BB 64
#define SS 512
#define EE 512
#define HH 1024
#define GG 4096
#define VV 32000

using bf16x8 = __attribute__((ext_vector_type(8))) __bf16;
using f32x4  = __attribute__((ext_vector_type(4))) float;

__device__ __forceinline__ unsigned short f2bf(float f) {
    unsigned u = __float_as_uint(f);
    unsigned r = u + 0x7FFFu + ((u >> 16) & 1u);   // RNE
    return (unsigned short)(r >> 16);
}
__device__ __forceinline__ float bf2f(unsigned short u) {
    return __uint_as_float(((unsigned)u) << 16);
}
__device__ __forceinline__ float sigm(float x) {
    return 1.0f / (1.0f + expf(-x));
}
// 16B fragment load via two agent-scope relaxed atomics (sc1 -> coherent at IF).
__device__ __forceinline__ bf16x8 ld_frag_coh(const unsigned long long* p) {
    union { unsigned long long u[2]; bf16x8 v; } x;
    x.u[0] = __hip_atomic_load(p,     __ATOMIC_RELAXED, __HIP_MEMORY_SCOPE_AGENT);
    x.u[1] = __hip_atomic_load(p + 1, __ATOMIC_RELAXED, __HIP_MEMORY_SCOPE_AGENT);
    return x.v;
}

// Packed-B layout: elem(nt, kt, lane, j) = B[kt*32 + (lane>>4)*8 + j][nt*16 + (lane&15)]
__global__ void pack_b(const float* __restrict__ B, unsigned short* __restrict__ out,
                       int KT, int N) {
    int bid = blockIdx.x;          // = nt*KT + kt
    int lane = threadIdx.x;
    int nt = bid / KT, kt = bid % KT;
    int k = kt * 32 + ((lane >> 4) << 3);
    int n = nt * 16 + (lane & 15);
    size_t base = ((size_t)bid * 64 + lane) * 8;
    #pragma unroll
    for (int j = 0; j < 8; ++j)
        out[base + j] = f2bf(B[(size_t)(k + j) * N + n]);
}

// Wh pack: colgroup g in [0,128) owns h-cols 8g..8g+7
// -> 32 gate-cols ordered n = q*8+cj (q=gate, cj=col offset), as 2 n-tiles.
// Frag id f = (g*2 + nt)*32 + kt.
__global__ void pack_wh(const float* __restrict__ Wh, unsigned short* __restrict__ out) {
    int f = blockIdx.x;            // (g*2 + nt)*32 + kt ; grid 8192
    int lane = threadIdx.x;
    int kt = f & 31, nt = (f >> 5) & 1, g = f >> 6;
    int nloc = lane & 15;
    int q = nt * 2 + (nloc >> 3), cj = nloc & 7;
    int gcol = q * HH + 8 * g + cj;
    int k = kt * 32 + ((lane >> 4) << 3);
    size_t base = ((size_t)f * 64 + lane) * 8;
    #pragma unroll
    for (int j = 0; j < 8; ++j)
        out[base + j] = f2bf(Wh[(size_t)(k + j) * GG + gcol]);
}

// Embedding gather written directly in packed-A form (M=32768 rows, K=512).
// Row order r = s*64 + b  (s-major, batch innermost).
__global__ void embed_pack(const int* __restrict__ x, const float* __restrict__ tab,
                           unsigned short* __restrict__ out) {
    int bid = blockIdx.x;          // = mt*16 + kt  (KT=16)
    int lane = threadIdx.x;
    int mt = bid >> 4, kt = bid & 15;
    int m = mt * 16 + (lane & 15);            // r = s*64 + b
    int idx = x[(m & 63) * SS + (m >> 6)];    // x is [B][S]
    int kb = kt * 32 + ((lane >> 4) << 3);
    size_t base = ((size_t)bid * 64 + lane) * 8;
    const float* src = tab + (size_t)idx * EE + kb;
    #pragma unroll
    for (int j = 0; j < 8; ++j)
        out[base + j] = f2bf(src[j]);
}

// C = A@B + bias.  MODE 0: float row-major (logits).
//                  MODE 1: bf16 x4s layout out[((s*GG + col)*64 + batch)],
//                          virtual row r = s*64 + batch; block owns one s x
//                          64 cols x 64 batches = contiguous 8KB region.
template<int MODE>
__global__ __launch_bounds__(256) void gemm_bias(
    const unsigned short* __restrict__ Ap, const unsigned short* __restrict__ Bp,
    const float* __restrict__ bias, void* __restrict__ Cout, int N, int KT) {
    __shared__ unsigned short tile[64][72];   // MODE1 transpose staging (padded)
    const int tid = threadIdx.x, lane = tid & 63, w = tid >> 6;
    const int ntg = blockIdx.x * 4 + w;
    const int m0t = blockIdx.y * 4;
    const bf16x8* Av = reinterpret_cast<const bf16x8*>(Ap);
    const bf16x8* Bv = reinterpret_cast<const bf16x8*>(Bp);
    f32x4 acc[4] = {{0.f,0.f,0.f,0.f},{0.f,0.f,0.f,0.f},{0.f,0.f,0.f,0.f},{0.f,0.f,0.f,0.f}};
    for (int kt = 0; kt < KT; ++kt) {
        bf16x8 b = Bv[((size_t)ntg * KT + kt) * 64 + lane];
        #pragma unroll
        for (int mt = 0; mt < 4; ++mt) {
            bf16x8 a = Av[((size_t)(m0t + mt) * KT + kt) * 64 + lane];
            acc[mt] = __builtin_amdgcn_mfma_f32_16x16x32_bf16(a, b, acc[mt], 0, 0, 0);
        }
    }
    const int col = ntg * 16 + (lane & 15);
    const int rq = (lane >> 4) << 2;
    const float bb = bias[col];
    if (MODE == 0) {
        #pragma unroll
        for (int mt = 0; mt < 4; ++mt)
            #pragma unroll
            for (int i = 0; i < 4; ++i) {
                int row = (m0t + mt) * 16 + rq + i;
                ((float*)Cout)[(size_t)row * N + col] = acc[mt][i] + bb;
            }
    } else {
        const int cl = w * 16 + (lane & 15);            // block-local col
        #pragma unroll
        for (int mt = 0; mt < 4; ++mt)
            #pragma unroll
            for (int i = 0; i < 4; ++i)
                tile[cl][mt * 16 + rq + i] = f2bf(acc[mt][i] + bb);
        __syncthreads();
        // linear 8KB store: out element (s*GG + col0)*64 + c*64 + b
        const int c = tid >> 2, b0 = (tid & 3) << 4;
        unsigned short* dst = (unsigned short*)Cout +
            ((size_t)blockIdx.y * GG + (size_t)blockIdx.x * 64) * 64 + (size_t)tid * 16;
        const uint4* s4 = reinterpret_cast<const uint4*>(&tile[c][b0]);
        reinterpret_cast<uint4*>(dst)[0] = s4[0];
        reinterpret_cast<uint4*>(dst)[1] = s4[1];
    }
}

// Zero h0 for both layers + all barrier flags (incl. go-flags at [8192,8256)).
__global__ void zero_init(unsigned short* __restrict__ h0a,
                          unsigned short* __restrict__ h0b,
                          unsigned int* __restrict__ flags) {
    int i = blockIdx.x * 256 + threadIdx.x;      // grid 64 x 256
    for (int k = i; k < BB * HH; k += 64 * 256) { h0a[k] = 0; h0b[k] = 0; }
    for (int k = i; k < 8256; k += 64 * 256) flags[k] = 0;
}

// Persistent LSTM layer. Grid 256 x 256 (cooperative).
// Block b: g = b>>1 (h-cols 8g..8g+7 -> 32 gate-cols), hf = b&1 (batch rows 32hf..+31).
// Waves: msub = w&1 (row-tile), kh = w>>1 (K-half) -> disjoint A fragments.
// Barrier: per-block done-flags; leader (g==0) polls all 128, then publishes a
// single go-flag everyone else polls (2-hop, tiny poll traffic).
__global__ __launch_bounds__(256, 1) void lstm_layer(
    const unsigned short* __restrict__ x4s, const unsigned short* __restrict__ whp,
    unsigned short* __restrict__ hbA, unsigned short* __restrict__ hbB,
    unsigned short* __restrict__ h1A, unsigned int* __restrict__ flagsL,
    unsigned int* __restrict__ gofL) {
    __shared__ float gx[2][32][36];                         // [khalf][n][block-row]
    __shared__ __align__(16) unsigned short hlds[32][8];    // gathered h chunks
    __shared__ __align__(16) unsigned short Blds[128 * 64 * 8];  // 64 KB Wh slice
    const int tid = threadIdx.x, lane = tid & 63, w = tid >> 6;
    const int g = blockIdx.x >> 1, hf = blockIdx.x & 1;
    unsigned int* flags = flagsL + hf * 2048;               // 128 flags x 16 u32 pad
    unsigned int* gof = gofL + hf * 16;                     // 1 go-flag per domain

    // ---- stage this colgroup's Wh slice (64 KB) into LDS, once ----
    {
        const uint4* src = reinterpret_cast<const uint4*>(whp) + (size_t)g * 4096;
        uint4* dst = reinterpret_cast<uint4*>(Blds);
        #pragma unroll
        for (int i = 0; i < 16; ++i)
            dst[i * 256 + tid] = src[i * 256 + tid];
    }
    __syncthreads();
    const bf16x8* Bl = reinterpret_cast<const bf16x8*>(Blds);

    const int msub = w & 1, kh = w >> 1;
    const int kh16 = kh * 16;
    const int nloc = lane & 15;
    const int cj = nloc & 7;
    const int q0 = nloc >> 3;                               // gate idx for nt=0
    const int gq0 = q0 * HH + 8 * g + cj;                   // nt=0 gate col
    const int gq1 = (2 + q0) * HH + 8 * g + cj;             // nt=1 gate col
    const int rbase = msub * 16 + ((lane >> 4) << 2);       // block-local row base
    const size_t afrag_base = ((size_t)(2 * hf + msub) * 32 + (size_t)kh * 16) * 64 + lane;

    // elementwise thread mapping
    const int row_l = tid >> 3, cj2 = tid & 7;
    float c = 0.f;

    #pragma unroll 1
    for (int t = 0; t < SS; ++t) {
        const unsigned long long* hv =
            reinterpret_cast<const unsigned long long*>((t & 1) ? hbB : hbA);
        unsigned short* hout = (t & 1) ? hbA : hbB;

        // ---- hoisted h-loads: issue all 16 fragments before any MFMA ----
        // (32 x 8B relaxed agent-scope loads, issued back-to-back in order;
        //  compiler inserts counted waits before first use -> 1 latency window)
        bf16x8 A[16];
        #pragma unroll
        for (int k = 0; k < 16; ++k)
            A[k] = ld_frag_coh(hv + (afrag_base + (size_t)k * 64) * 2);

        // ---- x4s prefetch (plain loads; latency hides under h window+MFMA) ----
        ushort4 xv0, xv1;
        if (kh == 0) {
            xv0 = *reinterpret_cast<const ushort4*>(
                x4s + ((size_t)t * GG + gq0) * 64 + 32 * hf + rbase);
            xv1 = *reinterpret_cast<const ushort4*>(
                x4s + ((size_t)t * GG + gq1) * 64 + 32 * hf + rbase);
        }

        f32x4 acc0 = {0.f, 0.f, 0.f, 0.f}, acc1 = {0.f, 0.f, 0.f, 0.f};
        #pragma unroll
        for (int k = 0; k < 16; ++k) {
            acc0 = __builtin_amdgcn_mfma_f32_16x16x32_bf16(
                A[k], Bl[(kh16 + k) * 64 + lane], acc0, 0, 0, 0);
            acc1 = __builtin_amdgcn_mfma_f32_16x16x32_bf16(
                A[k], Bl[(32 + kh16 + k) * 64 + lane], acc1, 0, 0, 0);
        }

        // write K-half partial sums (kh0 adds the x-projection)
        if (kh == 0) {
            gx[0][nloc][rbase + 0] = acc0[0] + bf2f(xv0.x);
            gx[0][nloc][rbase + 1] = acc0[1] + bf2f(xv0.y);
            gx[0][nloc][rbase + 2] = acc0[2] + bf2f(xv0.z);
            gx[0][nloc][rbase + 3] = acc0[3] + bf2f(xv0.w);
            gx[0][16 + nloc][rbase + 0] = acc1[0] + bf2f(xv1.x);
            gx[0][16 + nloc][rbase + 1] = acc1[1] + bf2f(xv1.y);
            gx[0][16 + nloc][rbase + 2] = acc1[2] + bf2f(xv1.z);
            gx[0][16 + nloc][rbase + 3] = acc1[3] + bf2f(xv1.w);
        } else {
            gx[1][nloc][rbase + 0] = acc0[0];
            gx[1][nloc][rbase + 1] = acc0[1];
            gx[1][nloc][rbase + 2] = acc0[2];
            gx[1][nloc][rbase + 3] = acc0[3];
            gx[1][16 + nloc][rbase + 0] = acc1[0];
            gx[1][16 + nloc][rbase + 1] = acc1[1];
            gx[1][16 + nloc][rbase + 2] = acc1[2];
            gx[1][16 + nloc][rbase + 3] = acc1[3];
        }
        __syncthreads();

        // elementwise: thread -> (row_l, cj2); n = q*8 + cj
        float gi = gx[0][0 * 8 + cj2][row_l] + gx[1][0 * 8 + cj2][row_l];
        float gf = gx[0][1 * 8 + cj2][row_l] + gx[1][1 * 8 + cj2][row_l];
        float gg = gx[0][2 * 8 + cj2][row_l] + gx[1][2 * 8 + cj2][row_l];
        float go = gx[0][3 * 8 + cj2][row_l] + gx[1][3 * 8 + cj2][row_l];
        float cn = sigm(gf) * c + sigm(gi) * tanhf(gg);
        c = cn;
        hlds[row_l][cj2] = f2bf(sigm(go) * tanhf(cn));
        __syncthreads();

        // gather 16B chunks; one full line per 4 rows, all owned by this block
        if (tid < 32) {
            union { uint4 v; unsigned long long u[2]; } cv;
            cv.v = *reinterpret_cast<const uint4*>(&hlds[tid][0]);
            const int m = 32 * hf + tid;
            unsigned long long* dst = reinterpret_cast<unsigned long long*>(
                hout + (((size_t)(m >> 4) * 32 + (g >> 2)) * 64 + (g & 3) * 16 + (m & 15)) * 8);
            __hip_atomic_store(dst,     cv.u[0], __ATOMIC_RELAXED, __HIP_MEMORY_SCOPE_AGENT);
            __hip_atomic_store(dst + 1, cv.u[1], __ATOMIC_RELAXED, __HIP_MEMORY_SCOPE_AGENT);
            if (h1A) {   // packed-A row r = t*64 + m (s-major order)
                const size_t mg = (size_t)t * 64 + m;
                *reinterpret_cast<uint4*>(
                    h1A + (((mg >> 4) * 32 + (size_t)(g >> 2)) * 64 + (g & 3) * 16 + (mg & 15)) * 8) = cv.v;
            }
        }

        // ---- release: drain own stores; then 2-hop flag barrier ----
        asm volatile("s_waitcnt vmcnt(0)" ::: "memory");
        __syncthreads();
        if (tid == 0)
            __hip_atomic_store(&flags[g * 16], (unsigned)(t + 1),
                               __ATOMIC_RELAXED, __HIP_MEMORY_SCOPE_AGENT);
        if (g == 0) {
            // leader: poll all 128 done flags, then publish go
            if (tid < 128) {
                while (__hip_atomic_load(&flags[tid * 16], __ATOMIC_RELAXED,
                                         __HIP_MEMORY_SCOPE_AGENT) < (unsigned)(t + 1))
                    __builtin_amdgcn_s_sleep(1);
            }
            __syncthreads();
            if (tid == 0)
                __hip_atomic_store(gof, (unsigned)(t + 1),
                                   __ATOMIC_RELAXED, __HIP_MEMORY_SCOPE_AGENT);
        } else {
            if (tid == 0) {
                while (__hip_atomic_load(gof, __ATOMIC_RELAXED,
                                         __HIP_MEMORY_SCOPE_AGENT) < (unsigned)(t + 1))
                    __builtin_amdgcn_s_sleep(1);
            }
            __syncthreads();
        }
    }
}

__global__ __launch_bounds__(256) void softmax_rows(const float* __restrict__ logits,
                                                    float* __restrict__ out) {
    __shared__ float red[256];
    int rr = blockIdx.x, tid = threadIdx.x;
    const float* L = logits + (size_t)rr * VV;
    float m = -1e30f;
    for (int i = tid; i < VV; i += 256) m = fmaxf(m, L[i]);
    red[tid] = m; __syncthreads();
    for (int s = 128; s > 0; s >>= 1) { if (tid < s) red[tid] = fmaxf(red[tid], red[tid + s]); __syncthreads(); }
    m = red[0]; __syncthreads();
    float sum = 0.f;
    for (int i = tid; i < VV; i += 256) sum += expf(L[i] - m);
    red[tid] = sum; __syncthreads();
    for (int s = 128; s > 0; s >>= 1) { if (tid < s) red[tid] += red[tid + s]; __syncthreads(); }
    float inv = 1.f / red[0];
    for (int i = tid; i < VV; i += 256) out[(size_t)rr * VV + i] = expf(L[i] - m) * inv;
}

extern "C" void kernel_launch(void* const* d_in, const int* in_sizes, int n_in,
                              void* d_out, int out_size, void* d_ws, size_t ws_size,
                              hipStream_t stream) {
    const int*   x    = (const int*)  d_in[0];
    const float* tab  = (const float*)d_in[1];
    const float* Wx0  = (const float*)d_in[2];
    const float* Wh0  = (const float*)d_in[3];
    const float* b0   = (const float*)d_in[4];
    const float* Wx1  = (const float*)d_in[5];
    const float* Wh1  = (const float*)d_in[6];
    const float* b1   = (const float*)d_in[7];
    const float* Wout = (const float*)d_in[8];
    const float* bout = (const float*)d_in[9];
    float* out = (float*)d_out;

    // ---- workspace layout (ushort units); all segments 16B-aligned ----
    unsigned short* ws    = (unsigned short*)d_ws;
    unsigned short* embA  = ws;                    // 16,777,216
    unsigned short* wx0p  = embA  + 16777216;      //  2,097,152
    unsigned short* wh0p  = wx0p  + 2097152;       //  4,194,304
    unsigned short* wx1p  = wh0p  + 4194304;       //  4,194,304
    unsigned short* wh1p  = wx1p  + 4194304;       //  4,194,304
    unsigned short* woutp = wh1p  + 4194304;       // 32,768,000
    unsigned short* x4s   = woutp + 32768000;      // 134,217,728 (reused by both layers)
    unsigned short* h1A   = x4s   + 134217728;     // 33,554,432
    unsigned short* hb0   = h1A   + 33554432;      // 65,536  (layer 0)
    unsigned short* hb1   = hb0   + 65536;         // 65,536
    unsigned short* hb2   = hb1   + 65536;         // 65,536  (layer 1)
    unsigned short* hb3   = hb2   + 65536;         // 65,536
    float* logits = (float*)(hb3 + 65536);         // 2,048,000 f32
    unsigned int* flags = (unsigned int*)(logits + 2048000);  // 8192 done + 64 go
    // total ~472 MB

    // ---- weight packing ----
    pack_b <<<256 * 16, 64, 0, stream>>>(Wx0, wx0p, 16, GG);
    pack_wh<<<8192, 64, 0, stream>>>(Wh0, wh0p);
    pack_b <<<256 * 32, 64, 0, stream>>>(Wx1, wx1p, 32, GG);
    pack_wh<<<8192, 64, 0, stream>>>(Wh1, wh1p);
    pack_b <<<2000 * 32, 64, 0, stream>>>(Wout, woutp, 32, VV);

    // ---- h0 + flag init ----
    zero_init<<<64, 256, 0, stream>>>(hb0, hb2, flags);

    // ---- embedding + layer-0 input projection ----
    embed_pack<<<32768, 64, 0, stream>>>(x, tab, embA);
    gemm_bias<1><<<dim3(GG / 64, 32768 / 64), 256, 0, stream>>>(embA, wx0p, b0, x4s, GG, EE / 32);

    // ---- layer 0 recurrence (persistent cooperative) ----
    {
        const unsigned short* a0 = x4s; const unsigned short* a1 = wh0p;
        unsigned short *a2 = hb0, *a3 = hb1, *a4 = h1A;
        unsigned int* a5 = flags;
        unsigned int* a6 = flags + 8192;
        void* args[] = {&a0, &a1, &a2, &a3, &a4, &a5, &a6};
        hipLaunchCooperativeKernel((const void*)lstm_layer, dim3(256), dim3(256),
                                   args, 0, stream);
    }

    // ---- layer-1 input projection + recurrence ----
    gemm_bias<1><<<dim3(GG / 64, 32768 / 64), 256, 0, stream>>>(h1A, wx1p, b1, x4s, GG, HH / 32);
    {
        const unsigned short* a0 = x4s; const unsigned short* a1 = wh1p;
        unsigned short *a2 = hb2, *a3 = hb3, *a4 = nullptr;
        unsigned int* a5 = flags + 4096;
        unsigned int* a6 = flags + 8192 + 32;
        void* args[] = {&a0, &a1, &a2, &a3, &a4, &a5, &a6};
        hipLaunchCooperativeKernel((const void*)lstm_layer, dim3(256), dim3(256),
                                   args, 0, stream);
    }
    // t=511 (odd) writes hb2

    // ---- logits (last timestep) + softmax ----
    gemm_bias<0><<<dim3(VV / 64, 1), 256, 0, stream>>>(hb2, woutp, bout, logits, VV, HH / 32);
    softmax_rows<<<64, 256, 0, stream>>>(logits, out);
}